// Round 1
// baseline (2110.188 us; speedup 1.0000x reference)
//
#include <hip/hip_runtime.h>

// entmax (alpha=1.5) via 5-section x 5-iter bisection, d=32000 per row.
// One 1024-thread block per row; row lives in registers (8 x float4 / thread).
// exponent = 1/(alpha-1) = 2 exactly -> probe mass is sum(relu(xs-tau)^2).

#define D 32000
#define NTHREADS 1024
#define CHUNK (NTHREADS * 4)   // 4096 elements per chunk
#define NCHUNK 8               // 8 * 4096 = 32768 >= 32000
#define ALPHA_M1 0.5f
#define TAU_HI_OFF 0.005590169943749474f   // (1/32000)^(alpha-1) = 1/sqrt(32000)
#define NEG_BIG (-1.0e30f)

__global__ __launch_bounds__(NTHREADS)
void entmax_nsect_kernel(const float* __restrict__ X, float* __restrict__ out) {
    const int row  = blockIdx.x;
    const int tid  = threadIdx.x;
    const int lane = tid & 63;
    const int wid  = tid >> 6;          // 16 waves

    const float* __restrict__ xrow = X   + (size_t)row * D;
    float* __restrict__       orow = out + (size_t)row * D;

    __shared__ float redf[64];          // 16 waves x up to 4 partials

    // ---- load row into registers, scaled by (alpha-1) ----
    float4 xs[NCHUNK];
    #pragma unroll
    for (int k = 0; k < NCHUNK; ++k) {
        const int off = k * CHUNK + tid * 4;
        if (off < D) {
            float4 v = *(const float4*)(xrow + off);
            xs[k].x = v.x * ALPHA_M1;
            xs[k].y = v.y * ALPHA_M1;
            xs[k].z = v.z * ALPHA_M1;
            xs[k].w = v.w * ALPHA_M1;
        } else {
            xs[k] = make_float4(NEG_BIG, NEG_BIG, NEG_BIG, NEG_BIG);
        }
    }

    // ---- block max ----
    float m = NEG_BIG;
    #pragma unroll
    for (int k = 0; k < NCHUNK; ++k)
        m = fmaxf(m, fmaxf(fmaxf(xs[k].x, xs[k].y), fmaxf(xs[k].z, xs[k].w)));
    #pragma unroll
    for (int o = 32; o >= 1; o >>= 1)
        m = fmaxf(m, __shfl_xor(m, o, 64));
    if (lane == 0) redf[wid] = m;
    __syncthreads();
    float mx = redf[0];
    #pragma unroll
    for (int w = 1; w < 16; ++w) mx = fmaxf(mx, redf[w]);

    float tau_lo = mx - 1.0f;
    float tau_hi = mx - TAU_HI_OFF;

    // ---- 5 bisection iterations, 4 probes each (all 4 in one register pass) ----
    for (int it = 0; it < 5; ++it) {
        const float width = (tau_hi - tau_lo) * 0.2f;
        const float t1 = tau_lo + 1.0f * width;
        const float t2 = tau_lo + 2.0f * width;
        const float t3 = tau_lo + 3.0f * width;
        const float t4 = tau_lo + 4.0f * width;

        float a1 = 0.f, a2 = 0.f, a3 = 0.f, a4 = 0.f;
        #pragma unroll
        for (int k = 0; k < NCHUNK; ++k) {
            float y, v;
            y = xs[k].x;
            v = fmaxf(y - t1, 0.f); a1 = fmaf(v, v, a1);
            v = fmaxf(y - t2, 0.f); a2 = fmaf(v, v, a2);
            v = fmaxf(y - t3, 0.f); a3 = fmaf(v, v, a3);
            v = fmaxf(y - t4, 0.f); a4 = fmaf(v, v, a4);
            y = xs[k].y;
            v = fmaxf(y - t1, 0.f); a1 = fmaf(v, v, a1);
            v = fmaxf(y - t2, 0.f); a2 = fmaf(v, v, a2);
            v = fmaxf(y - t3, 0.f); a3 = fmaf(v, v, a3);
            v = fmaxf(y - t4, 0.f); a4 = fmaf(v, v, a4);
            y = xs[k].z;
            v = fmaxf(y - t1, 0.f); a1 = fmaf(v, v, a1);
            v = fmaxf(y - t2, 0.f); a2 = fmaf(v, v, a2);
            v = fmaxf(y - t3, 0.f); a3 = fmaf(v, v, a3);
            v = fmaxf(y - t4, 0.f); a4 = fmaf(v, v, a4);
            y = xs[k].w;
            v = fmaxf(y - t1, 0.f); a1 = fmaf(v, v, a1);
            v = fmaxf(y - t2, 0.f); a2 = fmaf(v, v, a2);
            v = fmaxf(y - t3, 0.f); a3 = fmaf(v, v, a3);
            v = fmaxf(y - t4, 0.f); a4 = fmaf(v, v, a4);
        }
        // wave reduce the 4 partial masses
        #pragma unroll
        for (int o = 32; o >= 1; o >>= 1) {
            a1 += __shfl_xor(a1, o, 64);
            a2 += __shfl_xor(a2, o, 64);
            a3 += __shfl_xor(a3, o, 64);
            a4 += __shfl_xor(a4, o, 64);
        }
        __syncthreads();   // WAR: prior reads of redf complete before overwrite
        if (lane == 0) ((float4*)redf)[wid] = make_float4(a1, a2, a3, a4);
        __syncthreads();
        float m1 = 0.f, m2 = 0.f, m3 = 0.f, m4 = 0.f;
        #pragma unroll
        for (int w = 0; w < 16; ++w) {
            float4 r = ((float4*)redf)[w];
            m1 += r.x; m2 += r.y; m3 += r.z; m4 += r.w;
        }
        // largest probe with mass >= 1 (mass is decreasing in tau)
        int jb = 0;
        if (m1 >= 1.0f) jb = 1;
        if (m2 >= 1.0f) jb = 2;
        if (m3 >= 1.0f) jb = 3;
        if (m4 >= 1.0f) jb = 4;
        tau_lo = tau_lo + (float)jb * width;
        tau_hi = tau_lo + width;
    }

    // ---- final: p = relu(xs - tau_lo)^2, sum, normalize, store ----
    float s = 0.f;
    #pragma unroll
    for (int k = 0; k < NCHUNK; ++k) {
        float v;
        v = fmaxf(xs[k].x - tau_lo, 0.f); xs[k].x = v * v; s += xs[k].x;
        v = fmaxf(xs[k].y - tau_lo, 0.f); xs[k].y = v * v; s += xs[k].y;
        v = fmaxf(xs[k].z - tau_lo, 0.f); xs[k].z = v * v; s += xs[k].z;
        v = fmaxf(xs[k].w - tau_lo, 0.f); xs[k].w = v * v; s += xs[k].w;
    }
    #pragma unroll
    for (int o = 32; o >= 1; o >>= 1)
        s += __shfl_xor(s, o, 64);
    __syncthreads();
    if (lane == 0) redf[wid] = s;
    __syncthreads();
    float total = 0.f;
    #pragma unroll
    for (int w = 0; w < 16; ++w) total += redf[w];
    const float inv = 1.0f / total;

    #pragma unroll
    for (int k = 0; k < NCHUNK; ++k) {
        const int off = k * CHUNK + tid * 4;
        if (off < D) {
            float4 p = xs[k];
            p.x *= inv; p.y *= inv; p.z *= inv; p.w *= inv;
            *(float4*)(orow + off) = p;
        }
    }
}

extern "C" void kernel_launch(void* const* d_in, const int* in_sizes, int n_in,
                              void* d_out, int out_size, void* d_ws, size_t ws_size,
                              hipStream_t stream) {
    const float* X = (const float*)d_in[0];
    float* out = (float*)d_out;
    const int rows = in_sizes[0] / D;   // 8192
    entmax_nsect_kernel<<<rows, NTHREADS, 0, stream>>>(X, out);
}